// Round 7
// baseline (2234.020 us; speedup 1.0000x reference)
//
#include <hip/hip_runtime.h>
#include <math.h>

// Problem constants
#define NN 65536   // nodes
#define GG 128     // graphs
#define LL 512     // nodes per graph
#define DD 128     // feature dim
#define EE 262144  // edges
#define NSTEPS 6
#define CC 256     // concat dim
#define L1 510     // after k=3 valid conv
#define P1 254     // after pool(3,2)
#define P2 127     // after pool(2,2)

typedef __attribute__((ext_vector_type(8))) short s8bf;   // 8 bf16 in 4 VGPRs
typedef __attribute__((ext_vector_type(4))) float f4acc;  // MFMA accumulator

// fp32 -> bf16 (RNE) and back, as raw ushort
__device__ __forceinline__ unsigned short f2bf(float x) {
  unsigned u = __float_as_uint(x);
  unsigned r = u + 0x7FFFu + ((u >> 16) & 1u);
  return (unsigned short)(r >> 16);
}
__device__ __forceinline__ float bf2f(unsigned short h) {
  return __uint_as_float(((unsigned)h) << 16);
}
__device__ __forceinline__ unsigned short f2bf_sel(float x, int lo_sel) {
  unsigned short hi = f2bf(x);
  if (!lo_sel) return hi;
  return f2bf(x - bf2f(hi));
}
__device__ __forceinline__ uint2 pack4bf(float4 v, int lo_sel) {
  unsigned short s0 = f2bf_sel(v.x, lo_sel), s1 = f2bf_sel(v.y, lo_sel);
  unsigned short s2 = f2bf_sel(v.z, lo_sel), s3 = f2bf_sel(v.w, lo_sel);
  uint2 pk; pk.x = (unsigned)s0 | ((unsigned)s1 << 16);
  pk.y = (unsigned)s2 | ((unsigned)s3 << 16);
  return pk;
}

// ---------------------------------------------------------------------------
// prep: all weights to bf16 hi/lo in MFMA layouts.
// ---------------------------------------------------------------------------
__global__ __launch_bounds__(256) void k_prep(
    const float* __restrict__ wih, const float* __restrict__ whh,
    const float* __restrict__ gw,
    const float* __restrict__ w1, const float* __restrict__ wc1,
    const float* __restrict__ w2, const float* __restrict__ wc2,
    unsigned short* __restrict__ wihCh, unsigned short* __restrict__ wihCl,
    unsigned short* __restrict__ whhCh, unsigned short* __restrict__ whhCl,
    unsigned short* __restrict__ gwTh, unsigned short* __restrict__ gwTl,
    unsigned short* __restrict__ c1h, unsigned short* __restrict__ c1l,
    unsigned short* __restrict__ cc1h, unsigned short* __restrict__ cc1l,
    unsigned short* __restrict__ c2h, unsigned short* __restrict__ c2l,
    unsigned short* __restrict__ cc2h, unsigned short* __restrict__ cc2l) {
  int i = blockIdx.x * 256 + threadIdx.x;
  if (i < 49152) {  // GRU weights, elementwise hi/lo (already [384][128])
    float v = wih[i];
    unsigned short h_ = f2bf(v);
    wihCh[i] = h_; wihCl[i] = f2bf(v - bf2f(h_));
    float u = whh[i];
    unsigned short h2 = f2bf(u);
    whhCh[i] = h2; whhCl[i] = f2bf(u - bf2f(h2));
  }
  if (i < 98304) {  // gwT: i = s*16384 + col*128 + k
    int s = i >> 14; int r = i & 16383; int c = r >> 7; int k = r & 127;
    float v = gw[(s << 14) + k * 128 + c];
    unsigned short h_ = f2bf(v);
    gwTh[i] = h_; gwTl[i] = f2bf(v - bf2f(h_));
  }
  if (i < 49152) {  // c1: i = (tap*128+co)*128+ci ; src w1[co][ci][tap]
    int ci = i & 127; int r = i >> 7; int co = r & 127; int tap = r >> 7;
    float v = w1[(co * 128 + ci) * 3 + tap];
    unsigned short h_ = f2bf(v);
    c1h[i] = h_; c1l[i] = f2bf(v - bf2f(h_));
  }
  if (i < 196608) {  // cc1: i = (tap*256+co)*256+ci ; src wc1[co][ci][tap]
    int ci = i & 255; int r = i >> 8; int co = r & 255; int tap = r >> 8;
    float v = wc1[(co * 256 + ci) * 3 + tap];
    unsigned short h_ = f2bf(v);
    cc1h[i] = h_; cc1l[i] = f2bf(v - bf2f(h_));
  }
  if (i < 16384) {  // c2: identity layout [co][ci]
    float v = w2[i];
    unsigned short h_ = f2bf(v);
    c2h[i] = h_; c2l[i] = f2bf(v - bf2f(h_));
  }
  if (i < 65536) {  // cc2: identity layout [co][ci]
    float v = wc2[i];
    unsigned short h_ = f2bf(v);
    cc2h[i] = h_; cc2l[i] = f2bf(v - bf2f(h_));
  }
}

// ---------------------------------------------------------------------------
// CSR build (by dst) so the per-step aggregation is an atomic-free gather
// ---------------------------------------------------------------------------
__global__ __launch_bounds__(256) void k_hist(const int* __restrict__ dst, int* __restrict__ cnt) {
  int e = blockIdx.x * 256 + threadIdx.x;
  if (e < EE) atomicAdd(&cnt[dst[e]], 1);
}

__global__ __launch_bounds__(1024) void k_scan(const int* __restrict__ cnt,
                                               int* __restrict__ rowptr,
                                               int* __restrict__ cursor) {
  __shared__ int part[1024];
  int t = threadIdx.x;
  int base = t * 64;
  int s = 0;
  for (int i = 0; i < 64; i++) s += cnt[base + i];
  part[t] = s;
  __syncthreads();
  for (int off = 1; off < 1024; off <<= 1) {
    int v = part[t];
    int u = (t >= off) ? part[t - off] : 0;
    __syncthreads();
    part[t] = v + u;
    __syncthreads();
  }
  int run = part[t] - s;  // exclusive prefix of this chunk
  for (int i = 0; i < 64; i++) {
    rowptr[base + i] = run;
    cursor[base + i] = run;
    run += cnt[base + i];
  }
  if (t == 1023) rowptr[NN] = run;
}

__global__ __launch_bounds__(256) void k_fill(const int* __restrict__ src,
                                              const int* __restrict__ dst,
                                              const float* __restrict__ ew,
                                              int* __restrict__ cursor,
                                              int* __restrict__ col,
                                              float* __restrict__ wgt) {
  int e = blockIdx.x * 256 + threadIdx.x;
  if (e < EE) {
    int d = dst[e];
    int p = atomicAdd(&cursor[d], 1);
    col[p] = src[e];
    wgt[p] = ew[e];
  }
}

// ---------------------------------------------------------------------------
// m = h @ W via split-bf16 MFMA; B direct-from-global (tiny, L2-resident),
// A staged full-K in LDS once per A-precision. Pass order: hh, hl, lh.
// ---------------------------------------------------------------------------
__global__ __launch_bounds__(256, 4) void k_gemm_mfma(
    const float* __restrict__ A,
    const unsigned short* __restrict__ Wh, const unsigned short* __restrict__ Wl,
    float* __restrict__ Cout) {
  __shared__ __attribute__((aligned(16))) unsigned short As[64 * 136];
  int t = threadIdx.x;
  int r0 = blockIdx.x * 64;
  int wv = t >> 6, lane = t & 63;
  int ln = lane & 15, q = lane >> 4;
  f4acc acc[4][2];
#pragma unroll
  for (int mt = 0; mt < 4; mt++)
#pragma unroll
    for (int nt = 0; nt < 2; nt++) acc[mt][nt] = (f4acc)0.f;

  for (int p = 0; p < 3; p++) {
    if (p != 1) {  // stage A full K (hi at p0, lo at p2)
      const int a_lo = (p == 2);
      if (p) __syncthreads();
      for (int base = t * 4; base < 64 * 128; base += 1024) {
        int row = base >> 7, kk = base & 127;
        float4 v = *(const float4*)&A[(r0 + row) * 128 + kk];
        *(uint2*)&As[row * 136 + kk] = pack4bf(v, a_lo);
      }
      __syncthreads();
    }
    const unsigned short* W = (p == 1) ? Wl : Wh;
#pragma unroll
    for (int k0 = 0; k0 < 128; k0 += 32) {
      s8bf af[4], bf[2];
#pragma unroll
      for (int nt = 0; nt < 2; nt++)
        bf[nt] = *(const s8bf*)&W[(wv * 32 + nt * 16 + ln) * 128 + k0 + q * 8];
#pragma unroll
      for (int mt = 0; mt < 4; mt++)
        af[mt] = *(const s8bf*)&As[(mt * 16 + ln) * 136 + k0 + q * 8];
#pragma unroll
      for (int mt = 0; mt < 4; mt++)
#pragma unroll
        for (int nt = 0; nt < 2; nt++)
          acc[mt][nt] = __builtin_amdgcn_mfma_f32_16x16x32_bf16(af[mt], bf[nt], acc[mt][nt], 0, 0, 0);
    }
  }
#pragma unroll
  for (int mt = 0; mt < 4; mt++)
#pragma unroll
    for (int nt = 0; nt < 2; nt++)
#pragma unroll
      for (int reg = 0; reg < 4; reg++) {
        int r = r0 + mt * 16 + q * 4 + reg;
        Cout[r * 128 + wv * 32 + nt * 16 + ln] = acc[mt][nt][reg];
      }
}

// ---------------------------------------------------------------------------
// agg[n,:] = sum over in-edges of m[src,:]*w.  float4 lanes: 32 lanes/node,
// 8 nodes/block, 2-edge unroll for memory-level parallelism.
// ---------------------------------------------------------------------------
__global__ __launch_bounds__(256) void k_gather(const float* __restrict__ m,
                                                const int* __restrict__ rowptr,
                                                const int* __restrict__ col,
                                                const float* __restrict__ wgt,
                                                float* __restrict__ agg) {
  int t = threadIdx.x;
  int n = blockIdx.x * 8 + (t >> 5);
  int c4 = t & 31;
  const float4* m4 = (const float4*)m;
  int s0 = rowptr[n], s1 = rowptr[n + 1];
  float ax = 0.f, ay = 0.f, az = 0.f, aw = 0.f;
  int e = s0;
  for (; e + 2 <= s1; e += 2) {
    int cA = col[e], cB = col[e + 1];
    float wA = wgt[e], wB = wgt[e + 1];
    float4 vA = m4[cA * 32 + c4];
    float4 vB = m4[cB * 32 + c4];
    ax += vA.x * wA + vB.x * wB;
    ay += vA.y * wA + vB.y * wB;
    az += vA.z * wA + vB.z * wB;
    aw += vA.w * wA + vB.w * wB;
  }
  if (e < s1) {
    int cA = col[e];
    float wA = wgt[e];
    float4 vA = m4[cA * 32 + c4];
    ax += vA.x * wA; ay += vA.y * wA; az += vA.z * wA; aw += vA.w * wA;
  }
  ((float4*)agg)[n * 32 + c4] = make_float4(ax, ay, az, aw);
}

// ---------------------------------------------------------------------------
// Fused dual GEMM + GRU via split-bf16 MFMA. A staged full-K (both matrices);
// B staged per-k0-chunk in LDS (cuts L2 weight re-reads 8x vs direct loads).
// grid (1024, 2); NOT in-place.
// ---------------------------------------------------------------------------
__global__ __launch_bounds__(256, 2) void k_gru_mfma(
    const float* __restrict__ agg, const float* __restrict__ hin,
    const unsigned short* __restrict__ wihCh, const unsigned short* __restrict__ wihCl,
    const unsigned short* __restrict__ whhCh, const unsigned short* __restrict__ whhCl,
    const float* __restrict__ bih, const float* __restrict__ bhh,
    float* __restrict__ hout) {
  __shared__ __attribute__((aligned(16))) unsigned short As[2 * 64 * 136];  // [mat][row][k]
  __shared__ __attribute__((aligned(16))) unsigned short Bs[6 * 64 * 40];   // [tg][c][kk]
  int t = threadIdx.x;
  int r0 = blockIdx.x * 64;
  int d0 = blockIdx.y * 64;
  int wv = t >> 6, lane = t & 63;
  int ln = lane & 15, q = lane >> 4;
  f4acc acc[4][6];
#pragma unroll
  for (int mt = 0; mt < 4; mt++)
#pragma unroll
    for (int tg = 0; tg < 6; tg++) acc[mt][tg] = (f4acc)0.f;

  for (int p = 0; p < 3; p++) {
    const unsigned short* wx = (p == 1) ? wihCl : wihCh;
    const unsigned short* wh = (p == 1) ? whhCl : whhCh;
    for (int k0 = 0; k0 < 128; k0 += 32) {
      __syncthreads();  // protect As/Bs from previous chunk's readers
      if (k0 == 0 && p != 1) {  // stage A (both mats) full K: hi at p0, lo at p2
        const int a_lo = (p == 2);
#pragma unroll
        for (int mat = 0; mat < 2; mat++) {
          const float* Asrc = mat ? hin : agg;
          for (int base = t * 4; base < 64 * 128; base += 1024) {
            int row = base >> 7, kk = base & 127;
            float4 v = *(const float4*)&Asrc[(r0 + row) * 128 + kk];
            *(uint2*)&As[mat * 8704 + row * 136 + kk] = pack4bf(v, a_lo);
          }
        }
      }
      // stage B chunk: 6 tiles x 64 cols x 32 k
      for (int base = t * 4; base < 6 * 64 * 32; base += 1024) {
        int tg = base >> 11;
        int rem = base & 2047;
        int c = rem >> 5, kk = rem & 31;
        int gate = (tg < 3) ? tg : tg - 3;
        const unsigned short* W = (tg < 3) ? wx : wh;
        *(uint2*)&Bs[(tg * 64 + c) * 40 + kk] =
            *(const uint2*)&W[(gate * 128 + d0 + c) * 128 + k0 + kk];
      }
      __syncthreads();
      s8bf af[2][4], bfr[6];
#pragma unroll
      for (int tg = 0; tg < 6; tg++)
        bfr[tg] = *(const s8bf*)&Bs[(tg * 64 + wv * 16 + ln) * 40 + q * 8];
#pragma unroll
      for (int mat = 0; mat < 2; mat++)
#pragma unroll
        for (int mt = 0; mt < 4; mt++)
          af[mat][mt] = *(const s8bf*)&As[mat * 8704 + (mt * 16 + ln) * 136 + k0 + q * 8];
#pragma unroll
      for (int mt = 0; mt < 4; mt++)
#pragma unroll
        for (int tg = 0; tg < 6; tg++)
          acc[mt][tg] = __builtin_amdgcn_mfma_f32_16x16x32_bf16(
              af[tg < 3 ? 0 : 1][mt], bfr[tg], acc[mt][tg], 0, 0, 0);
    }
  }
  int d = d0 + wv * 16 + ln;
  float bi0 = bih[d], bi1 = bih[128 + d], bi2 = bih[256 + d];
  float bh0 = bhh[d], bh1 = bhh[128 + d], bh2 = bhh[256 + d];
#pragma unroll
  for (int mt = 0; mt < 4; mt++) {
#pragma unroll
    for (int reg = 0; reg < 4; reg++) {
      int r = r0 + mt * 16 + q * 4 + reg;
      float hold = hin[r * 128 + d];
      float xr = acc[mt][0][reg] + bi0;
      float xz = acc[mt][1][reg] + bi1;
      float xn = acc[mt][2][reg] + bi2;
      float hr = acc[mt][3][reg] + bh0;
      float hz = acc[mt][4][reg] + bh1;
      float hn = acc[mt][5][reg] + bh2;
      float rr = 1.f / (1.f + expf(-(xr + hr)));
      float zz = 1.f / (1.f + expf(-(xz + hz)));
      float nnv = tanhf(xn + rr * hn);
      hout[r * 128 + d] = (1.f - zz) * nnv + zz * hold;
    }
  }
}

// ---------------------------------------------------------------------------
// Generic implicit-GEMM conv via split-bf16 MFMA; B direct-from-global.
//  NT = 16-col tiles per wave; block covers 64*NT co (grid y = CIN/(64*NT)).
//  Input l-major: plane A [g][Lin][WA] (+ optional plane B for ch >= WA).
//  Weights [tap][co][ci] bf16 hi/lo. Output [g][Lco][CIN] + per-co stats.
// ---------------------------------------------------------------------------
template<int CIN, int TAPS, int WA, int NT>
__global__ __launch_bounds__(256, 3) void k_conv_mfma(
    const float* __restrict__ inA, const float* __restrict__ inB,
    const unsigned short* __restrict__ Wh, const unsigned short* __restrict__ Wl,
    const float* __restrict__ bias, float* __restrict__ out,
    float* __restrict__ stats, int Lin, int Lco) {
  constexpr int APAD = CIN + 8;
  constexpr int ROWS = 64 + TAPS - 1;
  constexpr int NCH = CIN / 32;
  constexpr int COB = 64 * NT;  // co per block
  __shared__ __attribute__((aligned(16))) unsigned short As[ROWS * APAD];
  __shared__ float sred[2 * COB];
  const int g = blockIdx.z, co0 = blockIdx.y * COB, l0 = blockIdx.x * 64;
  const int t = threadIdx.x;
  const int wv = t >> 6, lane = t & 63, ln = lane & 15, q = lane >> 4;
  f4acc acc[4][NT];
#pragma unroll
  for (int mt = 0; mt < 4; mt++)
#pragma unroll
    for (int nt = 0; nt < NT; nt++) acc[mt][nt] = (f4acc)0.f;

  // pass order: (Ah,Bh), (Ah,Bl), (Al,Bh)
  for (int p = 0; p < 3; p++) {
    if (p != 1) {
      const int a_lo = (p == 2);
      if (p) __syncthreads();
      for (int base = t * 4; base < ROWS * CIN; base += 1024) {
        int row = base / CIN, ch = base % CIN;
        int lr = l0 + row; if (lr > Lin - 1) lr = Lin - 1;
        float4 v;
        if (ch < WA) v = *(const float4*)&inA[(g * Lin + lr) * WA + ch];
        else         v = *(const float4*)&inB[(g * Lin + lr) * WA + ch - WA];
        *(uint2*)&As[row * APAD + ch] = pack4bf(v, a_lo);
      }
      __syncthreads();
    }
    const unsigned short* W = (p == 1) ? Wl : Wh;
#pragma unroll
    for (int tap = 0; tap < TAPS; tap++) {
#pragma unroll
      for (int ch = 0; ch < NCH; ch++) {
        const int c0 = ch * 32;
        s8bf af[4], bf[NT];
#pragma unroll
        for (int nt = 0; nt < NT; nt++)
          bf[nt] = *(const s8bf*)&W[(tap * CIN + co0 + wv * (NT * 16) + nt * 16 + ln) * CIN + c0 + q * 8];
#pragma unroll
        for (int mt = 0; mt < 4; mt++)
          af[mt] = *(const s8bf*)&As[(mt * 16 + ln + tap) * APAD + c0 + q * 8];
#pragma unroll
        for (int mt = 0; mt < 4; mt++)
#pragma unroll
          for (int nt = 0; nt < NT; nt++)
            acc[mt][nt] = __builtin_amdgcn_mfma_f32_16x16x32_bf16(af[mt], bf[nt], acc[mt][nt], 0, 0, 0);
      }
    }
  }
  // epilogue: bias, store [g][l][co], per-co sum/sumsq
  for (int i = t; i < 2 * COB; i += 256) sred[i] = 0.f;
  __syncthreads();
#pragma unroll
  for (int nt = 0; nt < NT; nt++) {
    int cl = wv * (NT * 16) + nt * 16 + ln;
    int co = co0 + cl;
    float bv = bias[co];
    float s = 0.f, s2 = 0.f;
#pragma unroll
    for (int mt = 0; mt < 4; mt++)
#pragma unroll
      for (int reg = 0; reg < 4; reg++) {
        int l = l0 + mt * 16 + q * 4 + reg;
        if (l < Lco) {
          float v = acc[mt][nt][reg] + bv;
          out[(g * Lco + l) * CIN + co] = v;
          s += v; s2 += v * v;
        }
      }
    atomicAdd(&sred[cl], s);
    atomicAdd(&sred[COB + cl], s2);
  }
  __syncthreads();
  for (int i = t; i < 2 * COB; i += 256) {
    int cl = (i < COB) ? i : i - COB;
    float* dstp = (i < COB) ? &stats[co0 + cl] : &stats[CIN + co0 + cl];
    atomicAdd(dstp, sred[i]);
  }
}

// ---------------------------------------------------------------------------
// BN(training stats) -> ReLU -> maxpool(pk, stride 2); l-major both sides
// ---------------------------------------------------------------------------
__global__ __launch_bounds__(256) void k_bnpool(const float* __restrict__ in,
                                                float* __restrict__ out,
                                                const float* __restrict__ stats,
                                                const float* __restrict__ gamma,
                                                const float* __restrict__ beta,
                                                int Cch, int LinC, int Lout, int pk) {
  int idx = blockIdx.x * 256 + threadIdx.x;
  int total = GG * Cch * Lout;
  if (idx >= total) return;
  int c = idx & (Cch - 1);
  int r = idx / Cch;
  int p = r % Lout;
  int g = r / Lout;
  float cntf = (float)(GG * LinC);
  float mean = stats[c] / cntf;
  float var = stats[Cch + c] / cntf - mean * mean;
  float inv = rsqrtf(var + 1e-5f) * gamma[c];
  float sh = beta[c] - mean * inv;
  const float* base = &in[((g * LinC) + 2 * p) * Cch + c];
  float m = 0.f;  // relu output >= 0
  for (int k = 0; k < pk; k++) {
    float v = fmaxf(base[k * Cch] * inv + sh, 0.f);
    m = fmaxf(m, v);
  }
  out[(g * Lout + p) * Cch + c] = m;
}

// ---------------------------------------------------------------------------
// final: Y2 [g][127][128], Z2 [g][127][256] l-major
// ---------------------------------------------------------------------------
__global__ __launch_bounds__(128) void k_final(const float* __restrict__ Y2,
                                               const float* __restrict__ Z2,
                                               const float* __restrict__ myw,
                                               const float* __restrict__ myb,
                                               const float* __restrict__ mzw,
                                               const float* __restrict__ mzb,
                                               float* __restrict__ outp) {
  __shared__ float red0[128];
  __shared__ float red1[128];
  int g = blockIdx.x;
  int t = threadIdx.x;
  float y0 = myb[0], y1 = myb[1], z0 = mzb[0], z1 = mzb[1];
  if (t < P2) {
    const float* yb = &Y2[(g * P2 + t) * 128];
    for (int c = 0; c < 128; c++) {
      float v = yb[c];
      y0 += v * myw[c];
      y1 += v * myw[128 + c];
    }
    const float* zb = &Z2[(g * P2 + t) * 256];
    for (int c = 0; c < 256; c++) {
      float v = zb[c];
      z0 += v * mzw[c];
      z1 += v * mzw[256 + c];
    }
  }
  red0[t] = (t < P2) ? y0 * z0 : 0.f;
  red1[t] = (t < P2) ? y1 * z1 : 0.f;
  __syncthreads();
  for (int off = 64; off > 0; off >>= 1) {
    if (t < off) {
      red0[t] += red0[t + off];
      red1[t] += red1[t + off];
    }
    __syncthreads();
  }
  if (t == 0) {
    outp[g * 2 + 0] = red0[0] / 127.f;
    outp[g * 2 + 1] = red1[0] / 127.f;
  }
}

// ---------------------------------------------------------------------------
extern "C" void kernel_launch(void* const* d_in, const int* in_sizes, int n_in,
                              void* d_out, int out_size, void* d_ws, size_t ws_size,
                              hipStream_t stream) {
  const float* x   = (const float*)d_in[0];
  const int* ei    = (const int*)d_in[1];
  const float* ew  = (const float*)d_in[2];
  // d_in[3] = batch: arange(N)//L -> pure reshape, unused
  const float* gw  = (const float*)d_in[4];
  const float* wih = (const float*)d_in[5];
  const float* whh = (const float*)d_in[6];
  const float* bih = (const float*)d_in[7];
  const float* bhh = (const float*)d_in[8];
  const float* w1  = (const float*)d_in[9];
  const float* b1  = (const float*)d_in[10];
  const float* w2  = (const float*)d_in[11];
  const float* b2  = (const float*)d_in[12];
  const float* wc1 = (const float*)d_in[13];
  const float* bc1 = (const float*)d_in[14];
  const float* wc2 = (const float*)d_in[15];
  const float* bc2 = (const float*)d_in[16];
  const float* bn1g = (const float*)d_in[17];
  const float* bn1b = (const float*)d_in[18];
  const float* bn2g = (const float*)d_in[19];
  const float* bn2b = (const float*)d_in[20];
  const float* myw = (const float*)d_in[21];
  const float* myb = (const float*)d_in[22];
  const float* mzw = (const float*)d_in[23];
  const float* mzb = (const float*)d_in[24];
  float* out = (float*)d_out;

  // workspace layout (floats)
  float* ws   = (float*)d_ws;
  float* h    = ws;                  // 8,388,608  (GRU ping buffer P; final h)
  float* bufA = h + 8388608;         // 16,711,680 (m / conv3 out [g][l][co])
  float* bufB = bufA + 16711680;     // 8,388,608  (agg / pool1 out [g][254][C])
  float* bufC = bufB + 8388608;      // 8,388,608  (GRU pong Q; conv1x1 out)
  float* Y2   = bufC + 8388608;      // 2,080,768  ([g][127][128])
  float* Z2   = Y2 + 2080768;        // 4,161,536  ([g][127][256])
  float* wslot = Z2 + 4161536;       // 98,304 floats = 4x49152 shorts (GRU bf16)
  unsigned short* wihCh = (unsigned short*)wslot;
  unsigned short* wihCl = wihCh + 49152;
  unsigned short* whhCh = wihCl + 49152;
  unsigned short* whhCl = whhCh + 49152;
  unsigned short* c1h  = (unsigned short*)(wslot + 98304);  // conv weights bf16
  unsigned short* c1l  = c1h + 49152;
  unsigned short* cc1h = c1l + 49152;
  unsigned short* cc1l = cc1h + 196608;
  unsigned short* c2h  = cc1l + 196608;
  unsigned short* c2l  = c2h + 16384;
  unsigned short* cc2h = c2l + 16384;
  unsigned short* cc2l = cc2h + 65536;
  float* stats = (float*)(cc2l + 65536);  // 512
  int* cnt    = (int*)(stats + 512); // 65,536
  int* rowptr = cnt + 65536;         // 65,537
  int* cursor = rowptr + 65537;      // 65,536
  int* col    = cursor + 65536;      // 262,144
  float* wgt  = (float*)(col + 262144);  // 262,144
  unsigned short* gwTh = (unsigned short*)(wgt + 262144);  // 98,304 shorts
  unsigned short* gwTl = gwTh + 98304;                     // 98,304 shorts
  size_t needed = (size_t)((float*)(gwTl + 98304) - ws) * 4;
  if (ws_size < needed) return;

  const int* src = ei;
  const int* dst = ei + EE;

  // one-time prep per launch
  k_prep<<<768, 256, 0, stream>>>(wih, whh, gw, w1, wc1, w2, wc2,
                                  wihCh, wihCl, whhCh, whhCl, gwTh, gwTl,
                                  c1h, c1l, cc1h, cc1l, c2h, c2l, cc2h, cc2l);
  hipMemsetAsync(cnt, 0, 65536 * 4, stream);
  k_hist<<<1024, 256, 0, stream>>>(dst, cnt);
  k_scan<<<1, 1024, 0, stream>>>(cnt, rowptr, cursor);
  k_fill<<<1024, 256, 0, stream>>>(src, dst, ew, cursor, col, wgt);

  // GGNN: 6 steps. Ping-pong h (P=h, Q=bufC): k_gru_mfma is d-sliced.
  float* P = h;
  float* Q = bufC;
  float* m = bufA;
  float* agg = bufB;
  for (int s = 0; s < NSTEPS; s++) {
    const float* hcur = (s == 0) ? x : ((s & 1) ? Q : P);
    float* hnext = (s & 1) ? P : Q;  // final (s=5) = P = h
    k_gemm_mfma<<<1024, 256, 0, stream>>>(hcur, gwTh + s * 16384, gwTl + s * 16384, m);
    k_gather<<<8192, 256, 0, stream>>>(m, rowptr, col, wgt, agg);
    k_gru_mfma<<<dim3(1024, 2), 256, 0, stream>>>(agg, hcur, wihCh, wihCl,
                                                  whhCh, whhCl, bih, bhh, hnext);
  }

  // Y path: conv3 -> bufA [g][510][128]; pool -> bufB [g][254][128];
  //         1x1 -> bufC [g][254][128]; pool -> Y2 [g][127][128]
  hipMemsetAsync(stats, 0, 512 * 4, stream);
  k_conv_mfma<128, 3, 128, 2><<<dim3(8, 1, 128), 256, 0, stream>>>(
      h, nullptr, c1h, c1l, b1, bufA, stats, 512, L1);
  k_bnpool<<<(GG * 128 * P1 + 255) / 256, 256, 0, stream>>>(bufA, bufB, stats, bn1g, bn1b, 128, L1, P1, 3);
  hipMemsetAsync(stats, 0, 512 * 4, stream);
  k_conv_mfma<128, 1, 128, 2><<<dim3(4, 1, 128), 256, 0, stream>>>(
      bufB, nullptr, c2h, c2l, b2, bufC, stats, P1, P1);
  k_bnpool<<<(GG * 128 * P2 + 255) / 256, 256, 0, stream>>>(bufC, Y2, stats, bn1g, bn1b, 128, P1, P2, 2);

  // Z path: conv3(concat h,x) -> bufA [g][510][256]; pool -> bufB [g][254][256];
  //         1x1 -> bufC [g][254][256]; pool -> Z2 [g][127][256]
  hipMemsetAsync(stats, 0, 512 * 4, stream);
  k_conv_mfma<256, 3, 128, 4><<<dim3(8, 1, 128), 256, 0, stream>>>(
      h, x, cc1h, cc1l, bc1, bufA, stats, 512, L1);
  k_bnpool<<<(GG * 256 * P1 + 255) / 256, 256, 0, stream>>>(bufA, bufB, stats, bn2g, bn2b, 256, L1, P1, 3);
  hipMemsetAsync(stats, 0, 512 * 4, stream);
  k_conv_mfma<256, 1, 256, 4><<<dim3(4, 1, 128), 256, 0, stream>>>(
      bufB, nullptr, cc2h, cc2l, bc2, bufC, stats, P1, P1);
  k_bnpool<<<(GG * 256 * P2 + 255) / 256, 256, 0, stream>>>(bufC, Z2, stats, bn2g, bn2b, 256, P1, P2, 2);

  // epilogue
  k_final<<<128, 128, 0, stream>>>(Y2, Z2, myw, myb, mzw, mzb, out);
}

// Round 8
// 1646.809 us; speedup vs baseline: 1.3566x; 1.3566x over previous
//
#include <hip/hip_runtime.h>
#include <math.h>

// Problem constants
#define NN 65536   // nodes
#define GG 128     // graphs
#define LL 512     // nodes per graph
#define DD 128     // feature dim
#define EE 262144  // edges
#define NSTEPS 6
#define CC 256     // concat dim
#define L1 510     // after k=3 valid conv
#define P1 254     // after pool(3,2)
#define P2 127     // after pool(2,2)

typedef __attribute__((ext_vector_type(8))) short s8bf;   // 8 bf16 in 4 VGPRs
typedef __attribute__((ext_vector_type(4))) float f4acc;  // MFMA accumulator

// fp32 -> bf16 (RNE) and back, as raw ushort
__device__ __forceinline__ unsigned short f2bf(float x) {
  unsigned u = __float_as_uint(x);
  unsigned r = u + 0x7FFFu + ((u >> 16) & 1u);
  return (unsigned short)(r >> 16);
}
__device__ __forceinline__ float bf2f(unsigned short h) {
  return __uint_as_float(((unsigned)h) << 16);
}
__device__ __forceinline__ unsigned short f2bf_sel(float x, int lo_sel) {
  unsigned short hi = f2bf(x);
  if (!lo_sel) return hi;
  return f2bf(x - bf2f(hi));
}
__device__ __forceinline__ uint2 pack4bf(float4 v, int lo_sel) {
  unsigned short s0 = f2bf_sel(v.x, lo_sel), s1 = f2bf_sel(v.y, lo_sel);
  unsigned short s2 = f2bf_sel(v.z, lo_sel), s3 = f2bf_sel(v.w, lo_sel);
  uint2 pk; pk.x = (unsigned)s0 | ((unsigned)s1 << 16);
  pk.y = (unsigned)s2 | ((unsigned)s3 << 16);
  return pk;
}

// ---------------------------------------------------------------------------
// prep: all weights to bf16 hi/lo in MFMA layouts.
// ---------------------------------------------------------------------------
__global__ __launch_bounds__(256) void k_prep(
    const float* __restrict__ wih, const float* __restrict__ whh,
    const float* __restrict__ gw,
    const float* __restrict__ w1, const float* __restrict__ wc1,
    const float* __restrict__ w2, const float* __restrict__ wc2,
    unsigned short* __restrict__ wihCh, unsigned short* __restrict__ wihCl,
    unsigned short* __restrict__ whhCh, unsigned short* __restrict__ whhCl,
    unsigned short* __restrict__ gwTh, unsigned short* __restrict__ gwTl,
    unsigned short* __restrict__ c1h, unsigned short* __restrict__ c1l,
    unsigned short* __restrict__ cc1h, unsigned short* __restrict__ cc1l,
    unsigned short* __restrict__ c2h, unsigned short* __restrict__ c2l,
    unsigned short* __restrict__ cc2h, unsigned short* __restrict__ cc2l) {
  int i = blockIdx.x * 256 + threadIdx.x;
  if (i < 49152) {  // GRU weights, elementwise hi/lo (already [384][128])
    float v = wih[i];
    unsigned short h_ = f2bf(v);
    wihCh[i] = h_; wihCl[i] = f2bf(v - bf2f(h_));
    float u = whh[i];
    unsigned short h2 = f2bf(u);
    whhCh[i] = h2; whhCl[i] = f2bf(u - bf2f(h2));
  }
  if (i < 98304) {  // gwT: i = s*16384 + col*128 + k
    int s = i >> 14; int r = i & 16383; int c = r >> 7; int k = r & 127;
    float v = gw[(s << 14) + k * 128 + c];
    unsigned short h_ = f2bf(v);
    gwTh[i] = h_; gwTl[i] = f2bf(v - bf2f(h_));
  }
  if (i < 49152) {  // c1: i = (tap*128+co)*128+ci ; src w1[co][ci][tap]
    int ci = i & 127; int r = i >> 7; int co = r & 127; int tap = r >> 7;
    float v = w1[(co * 128 + ci) * 3 + tap];
    unsigned short h_ = f2bf(v);
    c1h[i] = h_; c1l[i] = f2bf(v - bf2f(h_));
  }
  if (i < 196608) {  // cc1: i = (tap*256+co)*256+ci ; src wc1[co][ci][tap]
    int ci = i & 255; int r = i >> 8; int co = r & 255; int tap = r >> 8;
    float v = wc1[(co * 256 + ci) * 3 + tap];
    unsigned short h_ = f2bf(v);
    cc1h[i] = h_; cc1l[i] = f2bf(v - bf2f(h_));
  }
  if (i < 16384) {  // c2: identity layout [co][ci]
    float v = w2[i];
    unsigned short h_ = f2bf(v);
    c2h[i] = h_; c2l[i] = f2bf(v - bf2f(h_));
  }
  if (i < 65536) {  // cc2: identity layout [co][ci]
    float v = wc2[i];
    unsigned short h_ = f2bf(v);
    cc2h[i] = h_; cc2l[i] = f2bf(v - bf2f(h_));
  }
}

// ---------------------------------------------------------------------------
// CSR build (by dst) so the per-step aggregation is an atomic-free gather
// ---------------------------------------------------------------------------
__global__ __launch_bounds__(256) void k_hist(const int* __restrict__ dst, int* __restrict__ cnt) {
  int e = blockIdx.x * 256 + threadIdx.x;
  if (e < EE) atomicAdd(&cnt[dst[e]], 1);
}

__global__ __launch_bounds__(1024) void k_scan(const int* __restrict__ cnt,
                                               int* __restrict__ rowptr,
                                               int* __restrict__ cursor) {
  __shared__ int part[1024];
  int t = threadIdx.x;
  int base = t * 64;
  int s = 0;
  for (int i = 0; i < 64; i++) s += cnt[base + i];
  part[t] = s;
  __syncthreads();
  for (int off = 1; off < 1024; off <<= 1) {
    int v = part[t];
    int u = (t >= off) ? part[t - off] : 0;
    __syncthreads();
    part[t] = v + u;
    __syncthreads();
  }
  int run = part[t] - s;  // exclusive prefix of this chunk
  for (int i = 0; i < 64; i++) {
    rowptr[base + i] = run;
    cursor[base + i] = run;
    run += cnt[base + i];
  }
  if (t == 1023) rowptr[NN] = run;
}

__global__ __launch_bounds__(256) void k_fill(const int* __restrict__ src,
                                              const int* __restrict__ dst,
                                              const float* __restrict__ ew,
                                              int* __restrict__ cursor,
                                              int* __restrict__ col,
                                              float* __restrict__ wgt) {
  int e = blockIdx.x * 256 + threadIdx.x;
  if (e < EE) {
    int d = dst[e];
    int p = atomicAdd(&cursor[d], 1);
    col[p] = src[e];
    wgt[p] = ew[e];
  }
}

// ---------------------------------------------------------------------------
// m = h @ W via split-bf16 MFMA; B direct-from-global (tiny, L2-resident),
// A staged full-K in LDS once per A-precision. Pass order: hh, hl, lh.
// ---------------------------------------------------------------------------
__global__ __launch_bounds__(256, 4) void k_gemm_mfma(
    const float* __restrict__ A,
    const unsigned short* __restrict__ Wh, const unsigned short* __restrict__ Wl,
    float* __restrict__ Cout) {
  __shared__ __attribute__((aligned(16))) unsigned short As[64 * 136];
  int t = threadIdx.x;
  int r0 = blockIdx.x * 64;
  int wv = t >> 6, lane = t & 63;
  int ln = lane & 15, q = lane >> 4;
  f4acc acc[4][2];
#pragma unroll
  for (int mt = 0; mt < 4; mt++)
#pragma unroll
    for (int nt = 0; nt < 2; nt++) acc[mt][nt] = (f4acc)0.f;

  for (int p = 0; p < 3; p++) {
    if (p != 1) {  // stage A full K (hi at p0, lo at p2)
      const int a_lo = (p == 2);
      if (p) __syncthreads();
      for (int base = t * 4; base < 64 * 128; base += 1024) {
        int row = base >> 7, kk = base & 127;
        float4 v = *(const float4*)&A[(r0 + row) * 128 + kk];
        *(uint2*)&As[row * 136 + kk] = pack4bf(v, a_lo);
      }
      __syncthreads();
    }
    const unsigned short* W = (p == 1) ? Wl : Wh;
#pragma unroll
    for (int k0 = 0; k0 < 128; k0 += 32) {
      s8bf af[4], bf[2];
#pragma unroll
      for (int nt = 0; nt < 2; nt++)
        bf[nt] = *(const s8bf*)&W[(wv * 32 + nt * 16 + ln) * 128 + k0 + q * 8];
#pragma unroll
      for (int mt = 0; mt < 4; mt++)
        af[mt] = *(const s8bf*)&As[(mt * 16 + ln) * 136 + k0 + q * 8];
#pragma unroll
      for (int mt = 0; mt < 4; mt++)
#pragma unroll
        for (int nt = 0; nt < 2; nt++)
          acc[mt][nt] = __builtin_amdgcn_mfma_f32_16x16x32_bf16(af[mt], bf[nt], acc[mt][nt], 0, 0, 0);
    }
  }
#pragma unroll
  for (int mt = 0; mt < 4; mt++)
#pragma unroll
    for (int nt = 0; nt < 2; nt++)
#pragma unroll
      for (int reg = 0; reg < 4; reg++) {
        int r = r0 + mt * 16 + q * 4 + reg;
        Cout[r * 128 + wv * 32 + nt * 16 + ln] = acc[mt][nt][reg];
      }
}

// ---------------------------------------------------------------------------
// agg[n,:] = sum over in-edges of m[src,:]*w.  float4 lanes: 32 lanes/node,
// 8 nodes/block, 2-edge unroll for memory-level parallelism.
// ---------------------------------------------------------------------------
__global__ __launch_bounds__(256) void k_gather(const float* __restrict__ m,
                                                const int* __restrict__ rowptr,
                                                const int* __restrict__ col,
                                                const float* __restrict__ wgt,
                                                float* __restrict__ agg) {
  int t = threadIdx.x;
  int n = blockIdx.x * 8 + (t >> 5);
  int c4 = t & 31;
  const float4* m4 = (const float4*)m;
  int s0 = rowptr[n], s1 = rowptr[n + 1];
  float ax = 0.f, ay = 0.f, az = 0.f, aw = 0.f;
  int e = s0;
  for (; e + 2 <= s1; e += 2) {
    int cA = col[e], cB = col[e + 1];
    float wA = wgt[e], wB = wgt[e + 1];
    float4 vA = m4[cA * 32 + c4];
    float4 vB = m4[cB * 32 + c4];
    ax += vA.x * wA + vB.x * wB;
    ay += vA.y * wA + vB.y * wB;
    az += vA.z * wA + vB.z * wB;
    aw += vA.w * wA + vB.w * wB;
  }
  if (e < s1) {
    int cA = col[e];
    float wA = wgt[e];
    float4 vA = m4[cA * 32 + c4];
    ax += vA.x * wA; ay += vA.y * wA; az += vA.z * wA; aw += vA.w * wA;
  }
  ((float4*)agg)[n * 32 + c4] = make_float4(ax, ay, az, aw);
}

// ---------------------------------------------------------------------------
// Fused dual GEMM + GRU via split-bf16 MFMA; B direct-from-global,
// both A matrices (agg, hin) staged full-K in LDS. grid (1024, 2); NOT in-place.
// (round-6 structure: 3-4 barriers total — measured best)
// ---------------------------------------------------------------------------
__global__ __launch_bounds__(256, 2) void k_gru_mfma(
    const float* __restrict__ agg, const float* __restrict__ hin,
    const unsigned short* __restrict__ wihCh, const unsigned short* __restrict__ wihCl,
    const unsigned short* __restrict__ whhCh, const unsigned short* __restrict__ whhCl,
    const float* __restrict__ bih, const float* __restrict__ bhh,
    float* __restrict__ hout) {
  __shared__ __attribute__((aligned(16))) unsigned short As[2 * 64 * 136];  // [mat][row][k]
  int t = threadIdx.x;
  int r0 = blockIdx.x * 64;
  int d0 = blockIdx.y * 64;
  int wv = t >> 6, lane = t & 63;
  int ln = lane & 15, q = lane >> 4;
  f4acc acc[4][6];
#pragma unroll
  for (int mt = 0; mt < 4; mt++)
#pragma unroll
    for (int tg = 0; tg < 6; tg++) acc[mt][tg] = (f4acc)0.f;

  for (int p = 0; p < 3; p++) {
    if (p != 1) {  // stage A (both mats) full K: hi at p0, lo at p2
      const int a_lo = (p == 2);
      if (p) __syncthreads();
#pragma unroll
      for (int mat = 0; mat < 2; mat++) {
        const float* Asrc = mat ? hin : agg;
        for (int base = t * 4; base < 64 * 128; base += 1024) {
          int row = base >> 7, kk = base & 127;
          float4 v = *(const float4*)&Asrc[(r0 + row) * 128 + kk];
          *(uint2*)&As[mat * 8704 + row * 136 + kk] = pack4bf(v, a_lo);
        }
      }
      __syncthreads();
    }
    const unsigned short* wx = (p == 1) ? wihCl : wihCh;
    const unsigned short* wh = (p == 1) ? whhCl : whhCh;
#pragma unroll
    for (int k0 = 0; k0 < 128; k0 += 32) {
      s8bf af[2][4], bfr[6];
#pragma unroll
      for (int tg = 0; tg < 6; tg++) {
        int gate = (tg < 3) ? tg : tg - 3;
        const unsigned short* W = (tg < 3) ? wx : wh;
        bfr[tg] = *(const s8bf*)&W[(gate * 128 + d0 + wv * 16 + ln) * 128 + k0 + q * 8];
      }
#pragma unroll
      for (int mat = 0; mat < 2; mat++)
#pragma unroll
        for (int mt = 0; mt < 4; mt++)
          af[mat][mt] = *(const s8bf*)&As[mat * 8704 + (mt * 16 + ln) * 136 + k0 + q * 8];
#pragma unroll
      for (int mt = 0; mt < 4; mt++)
#pragma unroll
        for (int tg = 0; tg < 6; tg++)
          acc[mt][tg] = __builtin_amdgcn_mfma_f32_16x16x32_bf16(
              af[tg < 3 ? 0 : 1][mt], bfr[tg], acc[mt][tg], 0, 0, 0);
    }
  }
  int d = d0 + wv * 16 + ln;
  float bi0 = bih[d], bi1 = bih[128 + d], bi2 = bih[256 + d];
  float bh0 = bhh[d], bh1 = bhh[128 + d], bh2 = bhh[256 + d];
#pragma unroll
  for (int mt = 0; mt < 4; mt++) {
#pragma unroll
    for (int reg = 0; reg < 4; reg++) {
      int r = r0 + mt * 16 + q * 4 + reg;
      float hold = hin[r * 128 + d];
      float xr = acc[mt][0][reg] + bi0;
      float xz = acc[mt][1][reg] + bi1;
      float xn = acc[mt][2][reg] + bi2;
      float hr = acc[mt][3][reg] + bh0;
      float hz = acc[mt][4][reg] + bh1;
      float hn = acc[mt][5][reg] + bh2;
      float rr = 1.f / (1.f + expf(-(xr + hr)));
      float zz = 1.f / (1.f + expf(-(xz + hz)));
      float nnv = tanhf(xn + rr * hn);
      hout[r * 128 + d] = (1.f - zz) * nnv + zz * hold;
    }
  }
}

// ---------------------------------------------------------------------------
// Generic implicit-GEMM conv via split-bf16 MFMA; B direct-from-global.
//  (round-6 structure: NT=2 fixed, 128 co per block — measured best)
//  Input l-major: plane A [g][Lin][WA] (+ optional plane B for ch >= WA).
//  Weights [tap][co][ci] bf16 hi/lo. Output [g][Lco][CIN] + per-co stats.
//  Block: 64 l-rows x 128 co; grid (ceil(Lco/64), CIN/128, G).
// ---------------------------------------------------------------------------
template<int CIN, int TAPS, int WA>
__global__ __launch_bounds__(256, 3) void k_conv_mfma(
    const float* __restrict__ inA, const float* __restrict__ inB,
    const unsigned short* __restrict__ Wh, const unsigned short* __restrict__ Wl,
    const float* __restrict__ bias, float* __restrict__ out,
    float* __restrict__ stats, int Lin, int Lco) {
  constexpr int APAD = CIN + 8;
  constexpr int ROWS = 64 + TAPS - 1;
  constexpr int NCH = CIN / 32;
  __shared__ __attribute__((aligned(16))) unsigned short As[ROWS * APAD];
  __shared__ float sred[256];
  const int g = blockIdx.z, co0 = blockIdx.y * 128, l0 = blockIdx.x * 64;
  const int t = threadIdx.x;
  const int wv = t >> 6, lane = t & 63, ln = lane & 15, q = lane >> 4;
  f4acc acc[4][2];
#pragma unroll
  for (int mt = 0; mt < 4; mt++)
#pragma unroll
    for (int nt = 0; nt < 2; nt++) acc[mt][nt] = (f4acc)0.f;

  // pass order: (Ah,Bh), (Ah,Bl), (Al,Bh)
  for (int p = 0; p < 3; p++) {
    if (p != 1) {
      const int a_lo = (p == 2);
      if (p) __syncthreads();
      for (int base = t * 4; base < ROWS * CIN; base += 1024) {
        int row = base / CIN, ch = base % CIN;
        int lr = l0 + row; if (lr > Lin - 1) lr = Lin - 1;
        float4 v;
        if (ch < WA) v = *(const float4*)&inA[(g * Lin + lr) * WA + ch];
        else         v = *(const float4*)&inB[(g * Lin + lr) * WA + ch - WA];
        *(uint2*)&As[row * APAD + ch] = pack4bf(v, a_lo);
      }
      __syncthreads();
    }
    const unsigned short* W = (p == 1) ? Wl : Wh;
#pragma unroll
    for (int tap = 0; tap < TAPS; tap++) {
#pragma unroll
      for (int ch = 0; ch < NCH; ch++) {
        const int c0 = ch * 32;
        s8bf af[4], bf[2];
#pragma unroll
        for (int nt = 0; nt < 2; nt++)
          bf[nt] = *(const s8bf*)&W[(tap * CIN + co0 + wv * 32 + nt * 16 + ln) * CIN + c0 + q * 8];
#pragma unroll
        for (int mt = 0; mt < 4; mt++)
          af[mt] = *(const s8bf*)&As[(mt * 16 + ln + tap) * APAD + c0 + q * 8];
#pragma unroll
        for (int mt = 0; mt < 4; mt++)
#pragma unroll
          for (int nt = 0; nt < 2; nt++)
            acc[mt][nt] = __builtin_amdgcn_mfma_f32_16x16x32_bf16(af[mt], bf[nt], acc[mt][nt], 0, 0, 0);
      }
    }
  }
  // epilogue: bias, store [g][l][co], per-co sum/sumsq
  sred[t] = 0.f;
  __syncthreads();
#pragma unroll
  for (int nt = 0; nt < 2; nt++) {
    int cl = wv * 32 + nt * 16 + ln;
    int co = co0 + cl;
    float bv = bias[co];
    float s = 0.f, s2 = 0.f;
#pragma unroll
    for (int mt = 0; mt < 4; mt++)
#pragma unroll
      for (int reg = 0; reg < 4; reg++) {
        int l = l0 + mt * 16 + q * 4 + reg;
        if (l < Lco) {
          float v = acc[mt][nt][reg] + bv;
          out[(g * Lco + l) * CIN + co] = v;
          s += v; s2 += v * v;
        }
      }
    atomicAdd(&sred[cl], s);
    atomicAdd(&sred[128 + cl], s2);
  }
  __syncthreads();
  if (t < 128) atomicAdd(&stats[co0 + t], sred[t]);
  else atomicAdd(&stats[CIN + co0 + (t - 128)], sred[t]);
}

// ---------------------------------------------------------------------------
// BN(training stats) -> ReLU -> maxpool(pk, stride 2); l-major both sides
// ---------------------------------------------------------------------------
__global__ __launch_bounds__(256) void k_bnpool(const float* __restrict__ in,
                                                float* __restrict__ out,
                                                const float* __restrict__ stats,
                                                const float* __restrict__ gamma,
                                                const float* __restrict__ beta,
                                                int Cch, int LinC, int Lout, int pk) {
  int idx = blockIdx.x * 256 + threadIdx.x;
  int total = GG * Cch * Lout;
  if (idx >= total) return;
  int c = idx & (Cch - 1);
  int r = idx / Cch;
  int p = r % Lout;
  int g = r / Lout;
  float cntf = (float)(GG * LinC);
  float mean = stats[c] / cntf;
  float var = stats[Cch + c] / cntf - mean * mean;
  float inv = rsqrtf(var + 1e-5f) * gamma[c];
  float sh = beta[c] - mean * inv;
  const float* base = &in[((g * LinC) + 2 * p) * Cch + c];
  float m = 0.f;  // relu output >= 0
  for (int k = 0; k < pk; k++) {
    float v = fmaxf(base[k * Cch] * inv + sh, 0.f);
    m = fmaxf(m, v);
  }
  out[(g * Lout + p) * Cch + c] = m;
}

// ---------------------------------------------------------------------------
// final: Y2 [g][127][128], Z2 [g][127][256] l-major
// ---------------------------------------------------------------------------
__global__ __launch_bounds__(128) void k_final(const float* __restrict__ Y2,
                                               const float* __restrict__ Z2,
                                               const float* __restrict__ myw,
                                               const float* __restrict__ myb,
                                               const float* __restrict__ mzw,
                                               const float* __restrict__ mzb,
                                               float* __restrict__ outp) {
  __shared__ float red0[128];
  __shared__ float red1[128];
  int g = blockIdx.x;
  int t = threadIdx.x;
  float y0 = myb[0], y1 = myb[1], z0 = mzb[0], z1 = mzb[1];
  if (t < P2) {
    const float* yb = &Y2[(g * P2 + t) * 128];
    for (int c = 0; c < 128; c++) {
      float v = yb[c];
      y0 += v * myw[c];
      y1 += v * myw[128 + c];
    }
    const float* zb = &Z2[(g * P2 + t) * 256];
    for (int c = 0; c < 256; c++) {
      float v = zb[c];
      z0 += v * mzw[c];
      z1 += v * mzw[256 + c];
    }
  }
  red0[t] = (t < P2) ? y0 * z0 : 0.f;
  red1[t] = (t < P2) ? y1 * z1 : 0.f;
  __syncthreads();
  for (int off = 64; off > 0; off >>= 1) {
    if (t < off) {
      red0[t] += red0[t + off];
      red1[t] += red1[t + off];
    }
    __syncthreads();
  }
  if (t == 0) {
    outp[g * 2 + 0] = red0[0] / 127.f;
    outp[g * 2 + 1] = red1[0] / 127.f;
  }
}

// ---------------------------------------------------------------------------
extern "C" void kernel_launch(void* const* d_in, const int* in_sizes, int n_in,
                              void* d_out, int out_size, void* d_ws, size_t ws_size,
                              hipStream_t stream) {
  const float* x   = (const float*)d_in[0];
  const int* ei    = (const int*)d_in[1];
  const float* ew  = (const float*)d_in[2];
  // d_in[3] = batch: arange(N)//L -> pure reshape, unused
  const float* gw  = (const float*)d_in[4];
  const float* wih = (const float*)d_in[5];
  const float* whh = (const float*)d_in[6];
  const float* bih = (const float*)d_in[7];
  const float* bhh = (const float*)d_in[8];
  const float* w1  = (const float*)d_in[9];
  const float* b1  = (const float*)d_in[10];
  const float* w2  = (const float*)d_in[11];
  const float* b2  = (const float*)d_in[12];
  const float* wc1 = (const float*)d_in[13];
  const float* bc1 = (const float*)d_in[14];
  const float* wc2 = (const float*)d_in[15];
  const float* bc2 = (const float*)d_in[16];
  const float* bn1g = (const float*)d_in[17];
  const float* bn1b = (const float*)d_in[18];
  const float* bn2g = (const float*)d_in[19];
  const float* bn2b = (const float*)d_in[20];
  const float* myw = (const float*)d_in[21];
  const float* myb = (const float*)d_in[22];
  const float* mzw = (const float*)d_in[23];
  const float* mzb = (const float*)d_in[24];
  float* out = (float*)d_out;

  // workspace layout (floats)
  float* ws   = (float*)d_ws;
  float* h    = ws;                  // 8,388,608  (GRU ping buffer P; final h)
  float* bufA = h + 8388608;         // 16,711,680 (m / conv3 out [g][l][co])
  float* bufB = bufA + 16711680;     // 8,388,608  (agg / pool1 out [g][254][C])
  float* bufC = bufB + 8388608;      // 8,388,608  (GRU pong Q; conv1x1 out)
  float* Y2   = bufC + 8388608;      // 2,080,768  ([g][127][128])
  float* Z2   = Y2 + 2080768;        // 4,161,536  ([g][127][256])
  float* wslot = Z2 + 4161536;       // 98,304 floats = 4x49152 shorts (GRU bf16)
  unsigned short* wihCh = (unsigned short*)wslot;
  unsigned short* wihCl = wihCh + 49152;
  unsigned short* whhCh = wihCl + 49152;
  unsigned short* whhCl = whhCh + 49152;
  unsigned short* c1h  = (unsigned short*)(wslot + 98304);  // conv weights bf16
  unsigned short* c1l  = c1h + 49152;
  unsigned short* cc1h = c1l + 49152;
  unsigned short* cc1l = cc1h + 196608;
  unsigned short* c2h  = cc1l + 196608;
  unsigned short* c2l  = c2h + 16384;
  unsigned short* cc2h = c2l + 16384;
  unsigned short* cc2l = cc2h + 65536;
  float* stats = (float*)(cc2l + 65536);  // 512
  int* cnt    = (int*)(stats + 512); // 65,536
  int* rowptr = cnt + 65536;         // 65,537
  int* cursor = rowptr + 65537;      // 65,536
  int* col    = cursor + 65536;      // 262,144
  float* wgt  = (float*)(col + 262144);  // 262,144
  unsigned short* gwTh = (unsigned short*)(wgt + 262144);  // 98,304 shorts
  unsigned short* gwTl = gwTh + 98304;                     // 98,304 shorts
  size_t needed = (size_t)((float*)(gwTl + 98304) - ws) * 4;
  if (ws_size < needed) return;

  const int* src = ei;
  const int* dst = ei + EE;

  // one-time prep per launch
  k_prep<<<768, 256, 0, stream>>>(wih, whh, gw, w1, wc1, w2, wc2,
                                  wihCh, wihCl, whhCh, whhCl, gwTh, gwTl,
                                  c1h, c1l, cc1h, cc1l, c2h, c2l, cc2h, cc2l);
  hipMemsetAsync(cnt, 0, 65536 * 4, stream);
  k_hist<<<1024, 256, 0, stream>>>(dst, cnt);
  k_scan<<<1, 1024, 0, stream>>>(cnt, rowptr, cursor);
  k_fill<<<1024, 256, 0, stream>>>(src, dst, ew, cursor, col, wgt);

  // GGNN: 6 steps. Ping-pong h (P=h, Q=bufC): k_gru_mfma is d-sliced.
  float* P = h;
  float* Q = bufC;
  float* m = bufA;
  float* agg = bufB;
  for (int s = 0; s < NSTEPS; s++) {
    const float* hcur = (s == 0) ? x : ((s & 1) ? Q : P);
    float* hnext = (s & 1) ? P : Q;  // final (s=5) = P = h
    k_gemm_mfma<<<1024, 256, 0, stream>>>(hcur, gwTh + s * 16384, gwTl + s * 16384, m);
    k_gather<<<8192, 256, 0, stream>>>(m, rowptr, col, wgt, agg);
    k_gru_mfma<<<dim3(1024, 2), 256, 0, stream>>>(agg, hcur, wihCh, wihCl,
                                                  whhCh, whhCl, bih, bhh, hnext);
  }

  // Y path: conv3 -> bufA [g][510][128]; pool -> bufB [g][254][128];
  //         1x1 -> bufC [g][254][128]; pool -> Y2 [g][127][128]
  hipMemsetAsync(stats, 0, 512 * 4, stream);
  k_conv_mfma<128, 3, 128><<<dim3(8, 1, 128), 256, 0, stream>>>(
      h, nullptr, c1h, c1l, b1, bufA, stats, 512, L1);
  k_bnpool<<<(GG * 128 * P1 + 255) / 256, 256, 0, stream>>>(bufA, bufB, stats, bn1g, bn1b, 128, L1, P1, 3);
  hipMemsetAsync(stats, 0, 512 * 4, stream);
  k_conv_mfma<128, 1, 128><<<dim3(4, 1, 128), 256, 0, stream>>>(
      bufB, nullptr, c2h, c2l, b2, bufC, stats, P1, P1);
  k_bnpool<<<(GG * 128 * P2 + 255) / 256, 256, 0, stream>>>(bufC, Y2, stats, bn1g, bn1b, 128, P1, P2, 2);

  // Z path: conv3(concat h,x) -> bufA [g][510][256]; pool -> bufB [g][254][256];
  //         1x1 -> bufC [g][254][256]; pool -> Z2 [g][127][256]
  hipMemsetAsync(stats, 0, 512 * 4, stream);
  k_conv_mfma<256, 3, 128><<<dim3(8, 2, 128), 256, 0, stream>>>(
      h, x, cc1h, cc1l, bc1, bufA, stats, 512, L1);
  k_bnpool<<<(GG * 256 * P1 + 255) / 256, 256, 0, stream>>>(bufA, bufB, stats, bn2g, bn2b, 256, L1, P1, 3);
  hipMemsetAsync(stats, 0, 512 * 4, stream);
  k_conv_mfma<256, 1, 256><<<dim3(4, 2, 128), 256, 0, stream>>>(
      bufB, nullptr, cc2h, cc2l, bc2, bufC, stats, P1, P1);
  k_bnpool<<<(GG * 256 * P2 + 255) / 256, 256, 0, stream>>>(bufC, Z2, stats, bn2g, bn2b, 256, P1, P2, 2);

  // epilogue
  k_final<<<128, 128, 0, stream>>>(Y2, Z2, myw, myb, mzw, mzb, out);
}